// Round 19
// baseline (213.532 us; speedup 1.0000x reference)
//
#include <hip/hip_runtime.h>

#define MM 4096
#define NN 4096
#define KK 4096
#define BM 256
#define BN 256
#define BK 64
#define NT (KK / BK)
#define QSCALE 24.0f

typedef int           i32x4 __attribute__((ext_vector_type(4)));
typedef unsigned char uc8   __attribute__((ext_vector_type(8)));

#define MFMAI8(a, b, c) __builtin_amdgcn_mfma_i32_16x16x64_i8((a), (b), (c), 0, 0, 0)
#define SB0() __builtin_amdgcn_sched_barrier(0)
#define LGKM(n) asm volatile("s_waitcnt lgkmcnt(" #n ")" ::: "memory")
#define VMC(n)  asm volatile("s_waitcnt vmcnt(" #n ")" ::: "memory")

// ---------- helpers ----------

__device__ __forceinline__ void gload16(const void* g, void* l) {
  __builtin_amdgcn_global_load_lds(
      (const __attribute__((address_space(1))) void*)g,
      (__attribute__((address_space(3))) void*)l, 16, 0, 0);
}

__device__ __forceinline__ int q8(float v) {
  int q = (int)rintf(v * QSCALE);
  q = q > 127 ? 127 : q;
  q = q < -127 ? -127 : q;
  return q & 255;
}

// ---------- kernel 1: fused preprocessing (i8 outputs) ----------
// blocks [0, 8192):  2:4 mask + binarize -> wh i8 {0,1} (M x K)
// blocks [8192, 12288): x (K x N f32) -> xT i8 (N x K), 64x64 LDS transpose,
//   xq = clamp(rint(24*x), -127, 127)  (dequant scale 1/24 in GEMM epilogue)

__global__ __launch_bounds__(256) void kpre(const float* __restrict__ w,
                                            const float* __restrict__ x,
                                            signed char* __restrict__ wh,
                                            signed char* __restrict__ xt) {
  __shared__ float tile[64][65];
  const int t = threadIdx.x;

  if (blockIdx.x < 8192) {
    // ---- quant path ----
    int idx = blockIdx.x * 256 + t;
    const float4* p = (const float4*)w;
    float4 g0 = p[(size_t)idx * 2];
    float4 g1 = p[(size_t)idx * 2 + 1];
    float v[8] = {g0.x, g0.y, g0.z, g0.w, g1.x, g1.y, g1.z, g1.w};
    uc8 o;
#pragma unroll
    for (int g = 0; g < 2; g++) {
      float av[4];
#pragma unroll
      for (int j = 0; j < 4; j++) av[j] = fabsf(v[g * 4 + j]);
#pragma unroll
      for (int j = 0; j < 4; j++) {
        int rank = 0;
#pragma unroll
        for (int k = 0; k < 4; k++) {
          if (k == j) continue;
          rank += (av[k] > av[j] || (av[k] == av[j] && k < j)) ? 1 : 0;
        }
        o[g * 4 + j] = (rank < 2 && v[g * 4 + j] > 0.0f) ? (unsigned char)1
                                                         : (unsigned char)0;
      }
    }
    *(uc8*)(wh + (size_t)idx * 8) = o;
    return;
  }

  // ---- transpose + quantize path ----
  int bid2 = blockIdx.x - 8192;
  int bn = bid2 & 63;
  int bk = bid2 >> 6;
  int tc = (t & 15) << 2;
  int tr = t >> 4;
  const float* src = x + (size_t)(bk * 64 + tr) * NN + bn * 64 + tc;
#pragma unroll
  for (int i = 0; i < 4; i++) {
    float4 v = *(const float4*)(src + (size_t)i * 16 * NN);
    int r = tr + i * 16;
    tile[r][tc + 0] = v.x; tile[r][tc + 1] = v.y;
    tile[r][tc + 2] = v.z; tile[r][tc + 3] = v.w;
  }
  __syncthreads();
#pragma unroll
  for (int i = 0; i < 4; i++) {
    int n = tr + i * 16;
    unsigned int q = (unsigned)q8(tile[tc + 0][n])
                   | ((unsigned)q8(tile[tc + 1][n]) << 8)
                   | ((unsigned)q8(tile[tc + 2][n]) << 16)
                   | ((unsigned)q8(tile[tc + 3][n]) << 24);
    *(unsigned int*)(xt + (size_t)(bn * 64 + n) * KK + bk * 64 + tc) = q;
  }
}

// ---------- kernel 2: 256x256 i8 GEMM, TRIPLE-buffered, counted vmcnt ------
// 8 waves (2M x 4N), BK=64 = one mfma_i32_16x16x64_i8 K-step. LDS = 3 bufs x
// (A 16K + B 16K) = 96 KiB -> stage(t+2) overlaps stage(t+1)'s flight and the
// per-tile wait is VMC(4) (counted: waits only for loads issued a FULL TILE
// earlier) instead of the VMC(0) drain. Fragment registers double-buffered
// (sets S/S^1) so next-tile reads issue before Q-hi consumes this tile's.
// Per-tile order + ledger (in-order DS retire; per-wave):
//   [out=12: afl,bf,afh of t]  LGKM(4) => afl+bf ready -> Q-lo
//   LGKM(0) => afh ready; ALL my buf(t) reads retired
//   stage(t+2 -> buf (t+2)%3)   [safe: barrier(t-1) anchors all waves past
//                                their LGKM(0) of t-1 = buf(t-1) reads done]
//   VMC(4) => stage(t+1) landed (stage(t+2) still flying)
//   barrier => buf(t+1) collectively certified
//   read 12 of t+1 into set S^1 (drain under Q-hi)
//   Q-hi (afh_S x bf_S)

__global__ __launch_bounds__(512, 2) void kgemm(const signed char* __restrict__ A,
                                                const signed char* __restrict__ B,
                                                float* __restrict__ C) {
  __shared__ __align__(16) char lds[98304];  // A0|A1|A2 @0, B0|B1|B2 @49152

  const int tid  = threadIdx.x;
  // XCD swizzle: xcd = bid&7; each XCD owns a 4x8 rectangle of the 16x16 grid.
  const int bid  = blockIdx.x;
  const int xcd  = bid & 7;
  const int j    = bid >> 3;
  const int bmi  = (xcd >> 1) * 4 + (j >> 3);
  const int bni  = (xcd & 1) * 8 + (j & 7);
  const int lane = tid & 63;
  const int wave = tid >> 6;
  const int wm   = wave >> 2;
  const int wn   = wave & 3;
  const int llo  = lane & 15;
  const int lhi  = lane >> 4;

  // staging source (inverse-swizzled): thread t writes linear LDS granule t;
  // line L = t>>3, phys pos pgs = t&7; logical lg = pgs ^ (L&7);
  // row-in-chunk rl = 2L | lg>>2, k-quarter gq = lg&3.
  const int L   = tid >> 3;
  const int pgs = tid & 7;
  const int lg  = pgs ^ (L & 7);
  const int rl  = (L << 1) | (lg >> 2);
  const int gq  = lg & 3;
  const signed char* ga = A + (size_t)(bmi * BM + rl) * KK + gq * 16;
  const signed char* gb = B + (size_t)(bni * BN + rl) * KK + gq * 16;

  // fragment read offsets (verified r18): logical (row r, k-quarter lhi) at
  // chunk(r>>7)*8192 + (r&127 >>1)*128 + (((r&1)*4+lhi)^((r>>1)&7))*16
  const int pg   = (((llo & 1) << 2) + lhi) ^ ((llo >> 1) & 7);
  const int aoff = wm * 8192 + (llo >> 1) * 128 + pg * 16;            // + m*1024
  const int boff = (wn >> 1) * 8192 + ((wn & 1) * 32 + (llo >> 1)) * 128 + pg * 16;  // + n*1024

  i32x4 acc[8][4] = {};
  i32x4 afl[2][4], afh[2][4], bf[2][4];

  auto stage = [&](int buf, int t) {   // 2 A-gloads + 2 B-gloads
#pragma unroll
    for (int c = 0; c < 2; c++)
      gload16(ga + (size_t)c * 128 * KK + t * 64,
              lds + buf * 16384 + c * 8192 + tid * 16);
#pragma unroll
    for (int c = 0; c < 2; c++)
      gload16(gb + (size_t)c * 128 * KK + t * 64,
              lds + 49152 + buf * 16384 + c * 8192 + tid * 16);
  };
  auto readLoBF = [&](int s, int buf) {   // 8 reads (the LGKM(4)-gated group)
#pragma unroll
    for (int m = 0; m < 4; m++)
      afl[s][m] = *(const i32x4*)(lds + buf * 16384 + aoff + m * 1024);
#pragma unroll
    for (int n = 0; n < 4; n++)
      bf[s][n] = *(const i32x4*)(lds + 49152 + buf * 16384 + boff + n * 1024);
  };
  auto readHi = [&](int s, int buf) {     // 4 reads
#pragma unroll
    for (int m = 0; m < 4; m++)
      afh[s][m] = *(const i32x4*)(lds + buf * 16384 + aoff + (4 + m) * 1024);
  };

  // prologue: tiles 0,1 -> bufs 0,1; certify tile 0; issue its 12 reads
  stage(0, 0);
  stage(1, 1);
  VMC(4); SB0();                       // tile 0 landed; tile 1 flying
  __builtin_amdgcn_s_barrier(); SB0();
  readLoBF(0, 0); SB0();
  readHi(0, 0); SB0();

  for (int t = 0; t < NT; ++t) {
    const int S  = t & 1;
    const int b2 = (t + 2) % 3;
    const int b1 = (t + 1) % 3;
    const int tn = (t + 2) & (NT - 1);   // wraps on last iters (dead loads)

    // gate afl+bf (8 oldest of 12)
    LGKM(4); SB0();

    // Q-lo: afl_S x bf_S -> acc[0..3][*]
    __builtin_amdgcn_s_setprio(1);
#pragma unroll
    for (int m = 0; m < 4; m++)
#pragma unroll
      for (int n = 0; n < 4; n++)
        acc[m][n] = MFMAI8(afl[S][m], bf[S][n], acc[m][n]);
    __builtin_amdgcn_s_setprio(0);
    SB0();

    // gate afh; ALL my buf(t) reads now retired
    LGKM(0); SB0();

    // stage tile t+2 into buf (t+2)%3 = buf(t-1)
    stage(b2, tn); SB0();

    // counted wait: stage(t+1) landed, stage(t+2) still in flight
    VMC(4); SB0();
    __builtin_amdgcn_s_barrier(); SB0();

    // 12 reads of tile t+1 into the other fragment set (drain under Q-hi)
    readLoBF(S ^ 1, b1); SB0();
    readHi(S ^ 1, b1); SB0();

    // Q-hi: afh_S x bf_S -> acc[4..7][*]
    __builtin_amdgcn_s_setprio(1);
#pragma unroll
    for (int m = 0; m < 4; m++)
#pragma unroll
      for (int n = 0; n < 4; n++)
        acc[4 + m][n] = MFMAI8(afh[S][m], bf[S][n], acc[4 + m][n]);
    __builtin_amdgcn_s_setprio(0);
    SB0();
  }

  // ---- epilogue: D layout col = lane&15, row = (lane>>4)*4 + reg; scale 1/24
  const int crow0 = bmi * BM + wm * 128 + lhi * 4;
  const int ccol0 = bni * BN + wn * 64 + llo;
  const float ds = 1.0f / QSCALE;
#pragma unroll
  for (int m = 0; m < 8; m++)
#pragma unroll
    for (int n = 0; n < 4; n++) {
      float* cp = C + (size_t)(crow0 + m * 16) * NN + ccol0 + n * 16;
#pragma unroll
      for (int v = 0; v < 4; v++) cp[(size_t)v * NN] = (float)acc[m][n][v] * ds;
    }
}

// ---------- fallback: fused fp32 tiled GEMM (workspace too small) ----------

__device__ __forceinline__ float binq_elem(const float g[4], int j) {
  float aj = fabsf(g[j]);
  int rank = 0;
#pragma unroll
  for (int k = 0; k < 4; k++) {
    if (k == j) continue;
    float ak = fabsf(g[k]);
    rank += (ak > aj || (ak == aj && k < j)) ? 1 : 0;
  }
  return (rank < 2 && g[j] > 0.0f) ? 1.0f : 0.0f;
}

__global__ __launch_bounds__(256) void kfallback(const float* __restrict__ x,
                                                 const float* __restrict__ w,
                                                 float* __restrict__ c) {
  __shared__ float sA[16][17];
  __shared__ float sB[16][17];
  int tx = threadIdx.x, ty = threadIdx.y;
  int row = blockIdx.y * 16 + ty;
  int col = blockIdx.x * 16 + tx;
  float acc = 0.0f;
  for (int k0 = 0; k0 < KK; k0 += 16) {
    int k = k0 + tx;
    const float* g = &w[(size_t)row * KK + (k & ~3)];
    float gv[4] = {g[0], g[1], g[2], g[3]};
    sA[ty][tx] = binq_elem(gv, k & 3);
    sB[ty][tx] = x[(size_t)(k0 + ty) * NN + col];
    __syncthreads();
#pragma unroll
    for (int kk = 0; kk < 16; kk++) acc += sA[ty][kk] * sB[kk][tx];
    __syncthreads();
  }
  c[(size_t)row * NN + col] = acc;
}

// ---------- launcher ----------

extern "C" void kernel_launch(void* const* d_in, const int* in_sizes, int n_in,
                              void* d_out, int out_size, void* d_ws, size_t ws_size,
                              hipStream_t stream) {
  const float* x = (const float*)d_in[0];
  const float* w = (const float*)d_in[1];
  float* out = (float*)d_out;

  const size_t need = (size_t)MM * KK + (size_t)NN * KK;  // 33.6 MB (i8)
  if (ws_size < need) {
    dim3 blk(16, 16);
    dim3 grd(NN / 16, MM / 16);
    kfallback<<<grd, blk, 0, stream>>>(x, w, out);
    return;
  }

  signed char* wh = (signed char*)d_ws;
  signed char* xt = wh + (size_t)MM * KK;

  kpre<<<12288, 256, 0, stream>>>(w, x, wh, xt);
  kgemm<<<dim3((MM / BM) * (NN / BN)), 512, 0, stream>>>(wh, xt, out);
}

// Round 20
// 87.468 us; speedup vs baseline: 2.4413x; 2.4413x over previous
//
#include <hip/hip_runtime.h>

#define MM 4096
#define NN 4096
#define KK 4096
#define BM 256
#define BN 256
#define BK 64
#define NT (KK / BK)
#define QSCALE 24.0f

typedef int           i32x4 __attribute__((ext_vector_type(4)));
typedef unsigned char uc8   __attribute__((ext_vector_type(8)));

#define MFMAI8(a, b, c) __builtin_amdgcn_mfma_i32_16x16x64_i8((a), (b), (c), 0, 0, 0)
#define SB0() __builtin_amdgcn_sched_barrier(0)
#define LGKM(n) asm volatile("s_waitcnt lgkmcnt(" #n ")" ::: "memory")
#define VMC(n)  asm volatile("s_waitcnt vmcnt(" #n ")" ::: "memory")

// ---------- helpers ----------

__device__ __forceinline__ void gload16(const void* g, void* l) {
  __builtin_amdgcn_global_load_lds(
      (const __attribute__((address_space(1))) void*)g,
      (__attribute__((address_space(3))) void*)l, 16, 0, 0);
}

__device__ __forceinline__ int q8(float v) {
  int q = (int)rintf(v * QSCALE);
  q = q > 127 ? 127 : q;
  q = q < -127 ? -127 : q;
  return q & 255;
}

// ---------- kernel 1: fused preprocessing (i8 outputs) ----------
// blocks [0, 8192):  2:4 mask + binarize -> wh i8 {0,1} (M x K)
// blocks [8192, 12288): x (K x N f32) -> xT i8 (N x K), 64x64 LDS transpose,
//   xq = clamp(rint(24*x), -127, 127)  (dequant scale 1/24 in GEMM epilogue)

__global__ __launch_bounds__(256) void kpre(const float* __restrict__ w,
                                            const float* __restrict__ x,
                                            signed char* __restrict__ wh,
                                            signed char* __restrict__ xt) {
  __shared__ float tile[64][65];
  const int t = threadIdx.x;

  if (blockIdx.x < 8192) {
    // ---- quant path ----
    int idx = blockIdx.x * 256 + t;
    const float4* p = (const float4*)w;
    float4 g0 = p[(size_t)idx * 2];
    float4 g1 = p[(size_t)idx * 2 + 1];
    float v[8] = {g0.x, g0.y, g0.z, g0.w, g1.x, g1.y, g1.z, g1.w};
    uc8 o;
#pragma unroll
    for (int g = 0; g < 2; g++) {
      float av[4];
#pragma unroll
      for (int j = 0; j < 4; j++) av[j] = fabsf(v[g * 4 + j]);
#pragma unroll
      for (int j = 0; j < 4; j++) {
        int rank = 0;
#pragma unroll
        for (int k = 0; k < 4; k++) {
          if (k == j) continue;
          rank += (av[k] > av[j] || (av[k] == av[j] && k < j)) ? 1 : 0;
        }
        o[g * 4 + j] = (rank < 2 && v[g * 4 + j] > 0.0f) ? (unsigned char)1
                                                         : (unsigned char)0;
      }
    }
    *(uc8*)(wh + (size_t)idx * 8) = o;
    return;
  }

  // ---- transpose + quantize path ----
  int bid2 = blockIdx.x - 8192;
  int bn = bid2 & 63;
  int bk = bid2 >> 6;
  int tc = (t & 15) << 2;
  int tr = t >> 4;
  const float* src = x + (size_t)(bk * 64 + tr) * NN + bn * 64 + tc;
#pragma unroll
  for (int i = 0; i < 4; i++) {
    float4 v = *(const float4*)(src + (size_t)i * 16 * NN);
    int r = tr + i * 16;
    tile[r][tc + 0] = v.x; tile[r][tc + 1] = v.y;
    tile[r][tc + 2] = v.z; tile[r][tc + 3] = v.w;
  }
  __syncthreads();
#pragma unroll
  for (int i = 0; i < 4; i++) {
    int n = tr + i * 16;
    unsigned int q = (unsigned)q8(tile[tc + 0][n])
                   | ((unsigned)q8(tile[tc + 1][n]) << 8)
                   | ((unsigned)q8(tile[tc + 2][n]) << 16)
                   | ((unsigned)q8(tile[tc + 3][n]) << 24);
    *(unsigned int*)(xt + (size_t)(bn * 64 + n) * KK + bk * 64 + tc) = q;
  }
}

// ---------- kernel 2: 256x256 i8 GEMM, triple-buffer + counted vmcnt -------
// r19 schedule with the rule-#20 fix: fragment double-buffering via NAMED
// sets (A/B) + loop unrolled by 2, so every register index is compile-time
// (r19's afl[S][m] with runtime S put all fragments in scratch: WRITE_SIZE
// 457MB, 13% MfmaUtil). Ledger unchanged (verified r19, absmax OK):
//   [out=12 of t] LGKM(4) => afl+bf -> Q-lo ; LGKM(0) => afh + my buf(t)
//   reads retired ; stage(t+2 -> buf(t+2)%3) [barrier(t-1) anchors buf(t-1)
//   readers done] ; VMC(4) => stage(t+1) landed ; barrier => buf(t+1)
//   certified ; read 12 of t+1 into other set (drain under Q-hi) ; Q-hi.

__global__ __launch_bounds__(512, 2) void kgemm(const signed char* __restrict__ A,
                                                const signed char* __restrict__ B,
                                                float* __restrict__ C) {
  __shared__ __align__(16) char lds[98304];  // A0|A1|A2 @0, B0|B1|B2 @49152

  const int tid  = threadIdx.x;
  // XCD swizzle: xcd = bid&7; each XCD owns a 4x8 rectangle of the 16x16 grid.
  const int bid  = blockIdx.x;
  const int xcd  = bid & 7;
  const int j    = bid >> 3;
  const int bmi  = (xcd >> 1) * 4 + (j >> 3);
  const int bni  = (xcd & 1) * 8 + (j & 7);
  const int lane = tid & 63;
  const int wave = tid >> 6;
  const int wm   = wave >> 2;
  const int wn   = wave & 3;
  const int llo  = lane & 15;
  const int lhi  = lane >> 4;

  // staging source (inverse-swizzled): thread t writes linear LDS granule t;
  // line L = t>>3, phys pos pgs = t&7; logical lg = pgs ^ (L&7);
  // row-in-chunk rl = 2L | lg>>2, k-quarter gq = lg&3.
  const int L   = tid >> 3;
  const int pgs = tid & 7;
  const int lg  = pgs ^ (L & 7);
  const int rl  = (L << 1) | (lg >> 2);
  const int gq  = lg & 3;
  const signed char* ga = A + (size_t)(bmi * BM + rl) * KK + gq * 16;
  const signed char* gb = B + (size_t)(bni * BN + rl) * KK + gq * 16;

  // fragment read offsets (verified r18): logical (row r, k-quarter lhi) at
  // chunk(r>>7)*8192 + (r&127 >>1)*128 + (((r&1)*4+lhi)^((r>>1)&7))*16
  const int pg   = (((llo & 1) << 2) + lhi) ^ ((llo >> 1) & 7);
  const int aoff = wm * 8192 + (llo >> 1) * 128 + pg * 16;            // + m*1024
  const int boff = (wn >> 1) * 8192 + ((wn & 1) * 32 + (llo >> 1)) * 128 + pg * 16;  // + n*1024

  i32x4 acc[8][4] = {};
  i32x4 aflA[4], afhA[4], bfA[4];   // fragment set A (even tiles)
  i32x4 aflB[4], afhB[4], bfB[4];   // fragment set B (odd tiles)

  auto stage = [&](int buf, int t) {   // 2 A-gloads + 2 B-gloads
#pragma unroll
    for (int c = 0; c < 2; c++)
      gload16(ga + (size_t)c * 128 * KK + t * 64,
              lds + buf * 16384 + c * 8192 + tid * 16);
#pragma unroll
    for (int c = 0; c < 2; c++)
      gload16(gb + (size_t)c * 128 * KK + t * 64,
              lds + 49152 + buf * 16384 + c * 8192 + tid * 16);
  };
  auto readLoBF = [&](i32x4 (&afl)[4], i32x4 (&bf)[4], int buf) {  // 8 reads
#pragma unroll
    for (int m = 0; m < 4; m++)
      afl[m] = *(const i32x4*)(lds + buf * 16384 + aoff + m * 1024);
#pragma unroll
    for (int n = 0; n < 4; n++)
      bf[n] = *(const i32x4*)(lds + 49152 + buf * 16384 + boff + n * 1024);
  };
  auto readHi = [&](i32x4 (&afh)[4], int buf) {                    // 4 reads
#pragma unroll
    for (int m = 0; m < 4; m++)
      afh[m] = *(const i32x4*)(lds + buf * 16384 + aoff + (4 + m) * 1024);
  };

  // tile body: consume set C (tile t), prefetch set N (tile t+1)
  auto body = [&](i32x4 (&aflC)[4], i32x4 (&afhC)[4], i32x4 (&bfC)[4],
                  i32x4 (&aflN)[4], i32x4 (&afhN)[4], i32x4 (&bfN)[4], int t) {
    const int b2 = (t + 2) % 3;
    const int b1 = (t + 1) % 3;
    const int tn = (t + 2) & (NT - 1);   // wraps on last iters (dead loads)

    // gate aflC+bfC (8 oldest of 12)
    LGKM(4); SB0();

    // Q-lo: aflC x bfC -> acc[0..3][*]
    __builtin_amdgcn_s_setprio(1);
#pragma unroll
    for (int m = 0; m < 4; m++)
#pragma unroll
      for (int n = 0; n < 4; n++)
        acc[m][n] = MFMAI8(aflC[m], bfC[n], acc[m][n]);
    __builtin_amdgcn_s_setprio(0);
    SB0();

    // gate afhC; ALL my buf(t) reads now retired
    LGKM(0); SB0();

    // stage tile t+2 into buf (t+2)%3 = buf(t-1)
    stage(b2, tn); SB0();

    // counted wait: stage(t+1) landed, stage(t+2) still in flight
    VMC(4); SB0();
    __builtin_amdgcn_s_barrier(); SB0();

    // 12 reads of tile t+1 into the other named set (drain under Q-hi)
    readLoBF(aflN, bfN, b1); SB0();
    readHi(afhN, b1); SB0();

    // Q-hi: afhC x bfC -> acc[4..7][*]
    __builtin_amdgcn_s_setprio(1);
#pragma unroll
    for (int m = 0; m < 4; m++)
#pragma unroll
      for (int n = 0; n < 4; n++)
        acc[4 + m][n] = MFMAI8(afhC[m], bfC[n], acc[4 + m][n]);
    __builtin_amdgcn_s_setprio(0);
    SB0();
  };

  // prologue: tiles 0,1 -> bufs 0,1; certify tile 0; issue its 12 reads
  stage(0, 0);
  stage(1, 1);
  VMC(4); SB0();                       // tile 0 landed; tile 1 flying
  __builtin_amdgcn_s_barrier(); SB0();
  readLoBF(aflA, bfA, 0); SB0();
  readHi(afhA, 0); SB0();

  for (int it = 0; it < NT / 2; ++it) {
    body(aflA, afhA, bfA, aflB, afhB, bfB, 2 * it);
    body(aflB, afhB, bfB, aflA, afhA, bfA, 2 * it + 1);
  }

  // ---- epilogue: D layout col = lane&15, row = (lane>>4)*4 + reg; scale 1/24
  const int crow0 = bmi * BM + wm * 128 + lhi * 4;
  const int ccol0 = bni * BN + wn * 64 + llo;
  const float ds = 1.0f / QSCALE;
#pragma unroll
  for (int m = 0; m < 8; m++)
#pragma unroll
    for (int n = 0; n < 4; n++) {
      float* cp = C + (size_t)(crow0 + m * 16) * NN + ccol0 + n * 16;
#pragma unroll
      for (int v = 0; v < 4; v++) cp[(size_t)v * NN] = (float)acc[m][n][v] * ds;
    }
}

// ---------- fallback: fused fp32 tiled GEMM (workspace too small) ----------

__device__ __forceinline__ float binq_elem(const float g[4], int j) {
  float aj = fabsf(g[j]);
  int rank = 0;
#pragma unroll
  for (int k = 0; k < 4; k++) {
    if (k == j) continue;
    float ak = fabsf(g[k]);
    rank += (ak > aj || (ak == aj && k < j)) ? 1 : 0;
  }
  return (rank < 2 && g[j] > 0.0f) ? 1.0f : 0.0f;
}

__global__ __launch_bounds__(256) void kfallback(const float* __restrict__ x,
                                                 const float* __restrict__ w,
                                                 float* __restrict__ c) {
  __shared__ float sA[16][17];
  __shared__ float sB[16][17];
  int tx = threadIdx.x, ty = threadIdx.y;
  int row = blockIdx.y * 16 + ty;
  int col = blockIdx.x * 16 + tx;
  float acc = 0.0f;
  for (int k0 = 0; k0 < KK; k0 += 16) {
    int k = k0 + tx;
    const float* g = &w[(size_t)row * KK + (k & ~3)];
    float gv[4] = {g[0], g[1], g[2], g[3]};
    sA[ty][tx] = binq_elem(gv, k & 3);
    sB[ty][tx] = x[(size_t)(k0 + ty) * NN + col];
    __syncthreads();
#pragma unroll
    for (int kk = 0; kk < 16; kk++) acc += sA[ty][kk] * sB[kk][tx];
    __syncthreads();
  }
  c[(size_t)row * NN + col] = acc;
}

// ---------- launcher ----------

extern "C" void kernel_launch(void* const* d_in, const int* in_sizes, int n_in,
                              void* d_out, int out_size, void* d_ws, size_t ws_size,
                              hipStream_t stream) {
  const float* x = (const float*)d_in[0];
  const float* w = (const float*)d_in[1];
  float* out = (float*)d_out;

  const size_t need = (size_t)MM * KK + (size_t)NN * KK;  // 33.6 MB (i8)
  if (ws_size < need) {
    dim3 blk(16, 16);
    dim3 grd(NN / 16, MM / 16);
    kfallback<<<grd, blk, 0, stream>>>(x, w, out);
    return;
  }

  signed char* wh = (signed char*)d_ws;
  signed char* xt = wh + (size_t)MM * KK;

  kpre<<<12288, 256, 0, stream>>>(w, x, wh, xt);
  kgemm<<<dim3((MM / BM) * (NN / BN)), 512, 0, stream>>>(wh, xt, out);
}